// Round 8
// baseline (315.351 us; speedup 1.0000x reference)
//
#include <hip/hip_runtime.h>
#include <hip/hip_bf16.h>
#include <cstdint>

// ---------- types ----------
typedef __attribute__((ext_vector_type(8))) __bf16 bf16x8;
typedef __attribute__((ext_vector_type(4))) float  f32x4;

// float -> bf16 round-to-nearest-even
__device__ __forceinline__ unsigned short f2bf(float x) {
    union { float f; unsigned u; } v; v.f = x;
    unsigned r = v.u + 0x7fffu + ((v.u >> 16) & 1u);
    return (unsigned short)(r >> 16);
}
__device__ __forceinline__ unsigned pack2bf(float a, float b) {
    return (unsigned)f2bf(a) | ((unsigned)f2bf(b) << 16);
}

__device__ __forceinline__ void gld_lds16(const unsigned short* g, unsigned short* l) {
    __builtin_amdgcn_global_load_lds(
        (const __attribute__((address_space(1))) unsigned int*)g,
        (__attribute__((address_space(3))) unsigned int*)l,
        16, 0, 0);
}

// ---------- P0: fp32 -> bf16 convert ----------
__global__ void cvt_kernel(const float* __restrict__ in, unsigned short* __restrict__ out, int n4) {
    int i = blockIdx.x * blockDim.x + threadIdx.x;
    if (i < n4) {
        float4 f = ((const float4*)in)[i];
        ushort4 o;
        o.x = f2bf(f.x); o.y = f2bf(f.y); o.z = f2bf(f.z); o.w = f2bf(f.w);
        ((ushort4*)out)[i] = o;
    }
}

// ---------- P1: transpose-convert 1024x1024 fp32 W[k][n] -> bf16 out[n][k] ----------
__global__ void wtrans_kernel(const float* __restrict__ W, unsigned short* __restrict__ out) {
    __shared__ float tile[32][33];
    int bx = blockIdx.x, by = blockIdx.y;
    int tx = threadIdx.x, ty = threadIdx.y;
#pragma unroll
    for (int j = 0; j < 4; j++)
        tile[ty + j*8][tx] = W[(size_t)(bx*32 + ty + j*8) * 1024 + by*32 + tx];
    __syncthreads();
#pragma unroll
    for (int j = 0; j < 4; j++)
        out[(size_t)(by*32 + ty + j*8) * 1024 + bx*32 + tx] = f2bf(tile[tx][ty + j*8]);
}

// ---------- softmax: one block per row of 2048 bf16, in place ----------
__global__ void softmax_kernel(unsigned short* __restrict__ S) {
    const size_t row = blockIdx.x;
    unsigned short* p = S + row * 2048;
    const int tid = threadIdx.x;
    const int wave = tid >> 6, lane = tid & 63;

    uint4 raw = ((const uint4*)p)[tid];
    unsigned u[4] = {raw.x, raw.y, raw.z, raw.w};
    float x[8];
#pragma unroll
    for (int i = 0; i < 4; i++) {
        x[2*i]   = __uint_as_float(u[i] << 16);
        x[2*i+1] = __uint_as_float(u[i] & 0xffff0000u);
    }
    float m = x[0];
#pragma unroll
    for (int i = 1; i < 8; i++) m = fmaxf(m, x[i]);
#pragma unroll
    for (int off = 32; off >= 1; off >>= 1) m = fmaxf(m, __shfl_xor(m, off, 64));
    __shared__ float sm[4], ss[4];
    if (lane == 0) sm[wave] = m;
    __syncthreads();
    m = fmaxf(fmaxf(sm[0], sm[1]), fmaxf(sm[2], sm[3]));

    float e[8], s = 0.f;
#pragma unroll
    for (int i = 0; i < 8; i++) { e[i] = __expf(x[i] - m); s += e[i]; }
#pragma unroll
    for (int off = 32; off >= 1; off >>= 1) s += __shfl_xor(s, off, 64);
    if (lane == 0) ss[wave] = s;
    __syncthreads();
    s = ss[0] + ss[1] + ss[2] + ss[3];
    float inv = 1.0f / s;

    unsigned o[4];
#pragma unroll
    for (int i = 0; i < 4; i++)
        o[i] = pack2bf(e[2*i] * inv, e[2*i+1] * inv);
    ((uint4*)p)[tid] = make_uint4(o[0], o[1], o[2], o[3]);
}

// ---------- NT GEMM (R5 K-loop): C[m][n] = scale * sum_k A[m][k]*B[n][k] ----------
// 128x128 block tile, BK=64, 4 waves 64x64, 16x16x32 bf16 MFMA.
// A+B both DMA->LDS (xor-swizzled, conflict-free, coalesced) — best measured (R5).
// EPI: 0 = f32 + bias, transposed coalesced dwordx4 stores (G4)
//      1 = bf16 row-major, transposed coalesced stores (G2->Sc, G3->AO)
//      2 = G1 triple: Q[s][d], K[s][d] row-major + VT[d][s] transposed (kills vtrans)
template<int EPI>
__global__ __launch_bounds__(256)
void gemm_nt(const unsigned short* __restrict__ A, const unsigned short* __restrict__ B,
             void* __restrict__ C, unsigned short* __restrict__ CK, unsigned short* __restrict__ CV,
             const float* __restrict__ bias,
             int lda, int ldb, int ldc, int nk2, float scale,
             long long sA, long long sB, long long sC)
{
    // K-loop: A stage 16 KB (2 sub-tiles) + B stage 16 KB. Epilogue reuses
    // the first 17408 B as 4 per-wave 16x68-f32 scratches.
    __shared__ __align__(16) char smem[32768];
    unsigned short* As = (unsigned short*)smem;            // [2][128][32]
    unsigned short* Bs = (unsigned short*)(smem + 16384);  // [2][128][32]

    const int tid  = threadIdx.x;
    const int lane = tid & 63;
    const int wave = tid >> 6;
    const int bz = blockIdx.z;
    A += (size_t)bz * sA;
    B += (size_t)bz * sB;
    const int bm = blockIdx.y * 128;
    const int bn = blockIdx.x * 128;

    // staging: thread tid -> row tid>>2, chunk (tid&3)^((tid>>3)&3) within 64 B row
    const int srow = tid >> 2;
    const int scol = ((tid & 3) ^ ((tid >> 3) & 3)) * 8;
    const unsigned short* pa0 = A + (size_t)(bm + srow) * lda + scol;       // rows 0-63,  t0
    const unsigned short* pa1 = pa0 + 32;                                   // rows 0-63,  t1
    const unsigned short* pa2 = A + (size_t)(bm + 64 + srow) * lda + scol;  // rows 64-127,t0
    const unsigned short* pa3 = pa2 + 32;                                   // rows 64-127,t1
    const unsigned short* pb0 = B + (size_t)(bn + srow) * ldb + scol;
    const unsigned short* pb1 = pb0 + 32;
    const unsigned short* pb2 = B + (size_t)(bn + 64 + srow) * ldb + scol;
    const unsigned short* pb3 = pb2 + 32;

    f32x4 acc[4][4];
#pragma unroll
    for (int i = 0; i < 4; i++)
#pragma unroll
        for (int j = 0; j < 4; j++) acc[i][j] = (f32x4){0.f, 0.f, 0.f, 0.f};

    const int wm = (wave & 1) * 64;
    const int wn = (wave >> 1) * 64;
    const int ln15 = lane & 15;
    const int quad = lane >> 4;
    const int fko = (quad ^ ((ln15 >> 1) & 3)) * 8;   // swizzled frag k-offset (elems)
    const int ldsoff = tid * 16;

    for (int kt = 0; kt < nk2; ++kt) {
        __syncthreads();
        gld_lds16(pa0, (unsigned short*)(smem         + ldsoff));   // A t0 rows 0-63
        gld_lds16(pa2, (unsigned short*)(smem + 4096  + ldsoff));   // A t0 rows 64-127
        gld_lds16(pa1, (unsigned short*)(smem + 8192  + ldsoff));   // A t1 rows 0-63
        gld_lds16(pa3, (unsigned short*)(smem + 12288 + ldsoff));   // A t1 rows 64-127
        gld_lds16(pb0, (unsigned short*)(smem + 16384 + ldsoff));
        gld_lds16(pb2, (unsigned short*)(smem + 20480 + ldsoff));
        gld_lds16(pb1, (unsigned short*)(smem + 24576 + ldsoff));
        gld_lds16(pb3, (unsigned short*)(smem + 28672 + ldsoff));
        pa0 += 64; pa1 += 64; pa2 += 64; pa3 += 64;
        pb0 += 64; pb1 += 64; pb2 += 64; pb3 += 64;
        asm volatile("s_waitcnt vmcnt(0)" ::: "memory");
        __syncthreads();

#pragma unroll
        for (int t = 0; t < 2; t++) {
            bf16x8 af[4], bfr[4];
#pragma unroll
            for (int i = 0; i < 4; i++)
                af[i] = *(const bf16x8*)&As[t*4096 + (wm + i*16 + ln15) * 32 + fko];
#pragma unroll
            for (int j = 0; j < 4; j++)
                bfr[j] = *(const bf16x8*)&Bs[t*4096 + (wn + j*16 + ln15) * 32 + fko];
#pragma unroll
            for (int i = 0; i < 4; i++)
#pragma unroll
                for (int j = 0; j < 4; j++)
                    acc[i][j] = __builtin_amdgcn_mfma_f32_16x16x32_bf16(af[i], bfr[j], acc[i][j], 0, 0, 0);
        }
    }

    // ---------------- epilogue ----------------
    // C/D layout: col = ln15, row = quad*4 + reg. Per-wave 16x68 f32 scratch.
    __syncthreads();
    float* ep = (float*)(smem + wave * 4352);

    if (EPI == 0) {           // f32 + bias, coalesced
        float* Co = (float*)C + (size_t)bz * sC;
        const float* bp = bias + bn + wn;
#pragma unroll
        for (int i = 0; i < 4; i++) {
#pragma unroll
            for (int j = 0; j < 4; j++)
#pragma unroll
                for (int r = 0; r < 4; r++)
                    ep[(quad*4 + r) * 68 + j*16 + ln15] = acc[i][j][r] * scale;
            __builtin_amdgcn_s_waitcnt(0);
#pragma unroll
            for (int p = 0; p < 2; p++) {
                int lrow = p*8 + (lane >> 3);
                int col0 = (lane & 7) * 8;
                float4 lo = *(const float4*)&ep[lrow * 68 + col0];
                float4 hi = *(const float4*)&ep[lrow * 68 + col0 + 4];
                float4 b0 = *(const float4*)&bp[col0];
                float4 b1 = *(const float4*)&bp[col0 + 4];
                lo.x += b0.x; lo.y += b0.y; lo.z += b0.z; lo.w += b0.w;
                hi.x += b1.x; hi.y += b1.y; hi.z += b1.z; hi.w += b1.w;
                float* dst = &Co[(size_t)(bm + wm + i*16 + lrow) * ldc + bn + wn + col0];
                *(float4*)dst = lo;
                *(float4*)(dst + 4) = hi;
            }
            __builtin_amdgcn_s_waitcnt(0);
        }
    } else if (EPI == 1) {    // bf16 row-major, coalesced
        unsigned short* Co = (unsigned short*)C + (size_t)bz * sC;
#pragma unroll
        for (int i = 0; i < 4; i++) {
#pragma unroll
            for (int j = 0; j < 4; j++)
#pragma unroll
                for (int r = 0; r < 4; r++)
                    ep[(quad*4 + r) * 68 + j*16 + ln15] = acc[i][j][r] * scale;
            __builtin_amdgcn_s_waitcnt(0);
#pragma unroll
            for (int p = 0; p < 2; p++) {
                int lrow = p*8 + (lane >> 3);
                int col0 = (lane & 7) * 8;
                float4 lo = *(const float4*)&ep[lrow * 68 + col0];
                float4 hi = *(const float4*)&ep[lrow * 68 + col0 + 4];
                uint4 o;
                o.x = pack2bf(lo.x, lo.y); o.y = pack2bf(lo.z, lo.w);
                o.z = pack2bf(hi.x, hi.y); o.w = pack2bf(hi.z, hi.w);
                *(uint4*)&Co[(size_t)(bm + wm + i*16 + lrow) * ldc + bn + wn + col0] = o;
            }
            __builtin_amdgcn_s_waitcnt(0);
        }
    } else {                  // EPI == 2: Q / K row-major, VT transposed
        const int region = bn >> 10;           // 0=Q, 1=K, 2=V (block-uniform)
        const int b = bm >> 11;                // batch
#pragma unroll
        for (int i = 0; i < 4; i++) {
#pragma unroll
            for (int j = 0; j < 4; j++)
#pragma unroll
                for (int r = 0; r < 4; r++)
                    ep[(quad*4 + r) * 68 + j*16 + ln15] = acc[i][j][r];
            __builtin_amdgcn_s_waitcnt(0);
            if (region < 2) {
                unsigned short* Co = (region == 0) ? (unsigned short*)C : CK;
                int cn = (bn & 1023) + wn;
#pragma unroll
                for (int p = 0; p < 2; p++) {
                    int lrow = p*8 + (lane >> 3);
                    int col0 = (lane & 7) * 8;
                    float4 lo = *(const float4*)&ep[lrow * 68 + col0];
                    float4 hi = *(const float4*)&ep[lrow * 68 + col0 + 4];
                    uint4 o;
                    o.x = pack2bf(lo.x, lo.y); o.y = pack2bf(lo.z, lo.w);
                    o.z = pack2bf(hi.x, hi.y); o.w = pack2bf(hi.z, hi.w);
                    *(uint4*)&Co[(size_t)(bm + wm + i*16 + lrow) * 1024 + cn + col0] = o;
                }
            } else {
                // VT[b][d][s]: lane owns d-column (bn-2048)+wn+lane, 16 s-values
                float v[16];
#pragma unroll
                for (int r = 0; r < 16; r++) v[r] = ep[r * 68 + lane];
                unsigned o[8];
#pragma unroll
                for (int t = 0; t < 8; t++) o[t] = pack2bf(v[2*t], v[2*t+1]);
                int d = (bn - 2048) + wn + lane;
                int s0 = (bm & 2047) + wm + i*16;
                unsigned short* dst = CV + (size_t)b * 1024 * 2048 + (size_t)d * 2048 + s0;
                *(uint4*)dst       = make_uint4(o[0], o[1], o[2], o[3]);
                *(uint4*)(dst + 8) = make_uint4(o[4], o[5], o[6], o[7]);
            }
            __builtin_amdgcn_s_waitcnt(0);
        }
    }
}

// ---------- launcher ----------
extern "C" void kernel_launch(void* const* d_in, const int* in_sizes, int n_in,
                              void* d_out, int out_size, void* d_ws, size_t ws_size,
                              hipStream_t stream) {
    const float* X  = (const float*)d_in[0];   // [4,2048,1024]
    const float* Wq = (const float*)d_in[1];   // [1024,1024]
    const float* Wk = (const float*)d_in[2];
    const float* Wv = (const float*)d_in[3];
    const float* Wo = (const float*)d_in[4];
    const float* bo = (const float*)d_in[5];   // [1024]
    float* out = (float*)d_out;

    size_t off = 0;
    auto alloc = [&](size_t bytes) {
        void* p = (char*)d_ws + off;
        off += (bytes + 255) & ~(size_t)255;
        return p;
    };
    unsigned short* Xbf  = (unsigned short*)alloc(8192ull * 1024 * 2);      // 16 MB (reused as AO)
    unsigned short* Wcat = (unsigned short*)alloc(3072ull * 1024 * 2);      //  6 MB [n][k] q|k|v
    unsigned short* WoT  = (unsigned short*)alloc(1024ull * 1024 * 2);      //  2 MB [n][k]
    unsigned short* Qrm  = (unsigned short*)alloc(8192ull * 1024 * 2);      // 16 MB Q[s][d]
    unsigned short* Krm  = (unsigned short*)alloc(8192ull * 1024 * 2);      // 16 MB K[s][d]
    unsigned short* VT   = (unsigned short*)alloc(4ull * 1024 * 2048 * 2);  // 16 MB VT[b][d][s]
    unsigned short* Sc   = (unsigned short*)alloc(4ull * 2048 * 2048 * 2);  // 32 MB scores/probs
    unsigned short* AO   = Xbf;   // X dead after G1

    cvt_kernel<<<(8192*1024/4 + 255)/256, 256, 0, stream>>>(X, Xbf, 8192*1024/4);
    dim3 tb(32, 8);
    wtrans_kernel<<<dim3(32,32), tb, 0, stream>>>(Wq, Wcat);
    wtrans_kernel<<<dim3(32,32), tb, 0, stream>>>(Wk, Wcat + 1024*1024);
    wtrans_kernel<<<dim3(32,32), tb, 0, stream>>>(Wv, Wcat + 2*1024*1024);
    wtrans_kernel<<<dim3(32,32), tb, 0, stream>>>(Wo, WoT);

    // G1: [Q|K|V] = Xbf @ Wcat^T   M=8192 N=3072 K=1024
    gemm_nt<2><<<dim3(3072/128, 8192/128, 1), 256, 0, stream>>>(
        Xbf, Wcat, Qrm, Krm, VT, nullptr, 1024, 1024, 0, 16, 1.0f, 0, 0, 0);

    // G2: Sc = (Q @ K^T)/32 per batch   M=N=2048 K=1024
    gemm_nt<1><<<dim3(2048/128, 2048/128, 4), 256, 0, stream>>>(
        Qrm, Krm, Sc, nullptr, nullptr, nullptr, 1024, 1024, 2048, 16, 0.03125f,
        2048ll*1024, 2048ll*1024, 2048ll*2048);

    softmax_kernel<<<8192, 256, 0, stream>>>(Sc);

    // G3: AO = P @ V per batch   M=2048 N=1024 K=2048  (B = VT[d][s])
    gemm_nt<1><<<dim3(1024/128, 2048/128, 4), 256, 0, stream>>>(
        Sc, VT, AO, nullptr, nullptr, nullptr, 2048, 2048, 1024, 32, 1.0f,
        2048ll*2048, 1024ll*2048, 2048ll*1024);

    // G4: out = AO @ WoT^T + bo   M=8192 N=1024 K=1024, f32 out
    gemm_nt<0><<<dim3(1024/128, 8192/128, 1), 256, 0, stream>>>(
        AO, WoT, out, nullptr, nullptr, bo, 1024, 1024, 1024, 16, 1.0f, 0, 0, 0);

    (void)n_in; (void)in_sizes; (void)out_size; (void)ws_size;
}